// Round 3
// baseline (278.372 us; speedup 1.0000x reference)
//
#include <hip/hip_runtime.h>
#include <hip/hip_bf16.h>

// FastBinaryLinear: y[t,o] = scale[o] * sum_i x[t,i]*sign(w[o,i])
// Pre-pass: x->bf16, w->sign(w) bf16 into d_ws. Main: 256x256 8-phase bf16
// MFMA GEMM. R3: ds_reads moved AFTER each MFMA cluster (async overlap, no
// lgkm stall in lockstep), + bijective XCD-aware block swizzle (T1).

typedef __bf16 bf16x8 __attribute__((ext_vector_type(8)));
typedef float f32x4 __attribute__((ext_vector_type(4)));
typedef const __attribute__((address_space(1))) void* gptr_t;
typedef __attribute__((address_space(3))) void* lptr_t;

#define LDS_BUF 65536

template<bool V> struct BoolC { static constexpr bool value = V; };

// ---- f32 -> bf16 RNE ----
__device__ __forceinline__ unsigned short f32_to_bf16_rne(float f) {
  unsigned int u = __builtin_bit_cast(unsigned int, f);
  u += 0x7fffu + ((u >> 16) & 1u);
  return (unsigned short)(u >> 16);
}

__global__ __launch_bounds__(256) void cvt_x_kernel(const float4* __restrict__ in,
                                                    ushort4* __restrict__ out, int n4) {
  int stride = gridDim.x * blockDim.x;
  for (int i = blockIdx.x * blockDim.x + threadIdx.x; i < n4; i += stride) {
    float4 f = in[i];
    ushort4 o;
    o.x = f32_to_bf16_rne(f.x);
    o.y = f32_to_bf16_rne(f.y);
    o.z = f32_to_bf16_rne(f.z);
    o.w = f32_to_bf16_rne(f.w);
    out[i] = o;
  }
}

__device__ __forceinline__ unsigned short sign_bf16(float f) {
  return f > 0.f ? (unsigned short)0x3F80u : (f < 0.f ? (unsigned short)0xBF80u : (unsigned short)0u);
}

__global__ __launch_bounds__(256) void binarize_w_kernel(const float4* __restrict__ in,
                                                         ushort4* __restrict__ out, int n4) {
  int stride = gridDim.x * blockDim.x;
  for (int i = blockIdx.x * blockDim.x + threadIdx.x; i < n4; i += stride) {
    float4 f = in[i];
    ushort4 o;
    o.x = sign_bf16(f.x);
    o.y = sign_bf16(f.y);
    o.z = sign_bf16(f.z);
    o.w = sign_bf16(f.w);
    out[i] = o;
  }
}

template<int MF0>
__device__ __forceinline__ void mfma16(f32x4 (&acc)[8][4], const bf16x8 (&a0)[2][2],
                                       const bf16x8 (&b0)[4][2]) {
#pragma unroll
  for (int j = 0; j < 2; j++)
#pragma unroll
    for (int nf = 0; nf < 4; nf++)
#pragma unroll
      for (int kk = 0; kk < 2; kk++)
        acc[MF0 + j][nf] =
            __builtin_amdgcn_mfma_f32_16x16x32_bf16(a0[j][kk], b0[nf][kk], acc[MF0 + j][nf], 0, 0, 0);
}

// ---- 256x256 8-phase GEMM: C[M][N] = A[M][K] * B[N][K]^T, per-col scale ----
__global__ __launch_bounds__(512, 2) void gemm256_kernel(
    const __hip_bfloat16* __restrict__ A,   // [M][K] bf16
    const __hip_bfloat16* __restrict__ B,   // [N][K] bf16 (+-1/0)
    const float* __restrict__ scale,        // [N]
    float* __restrict__ C,                  // [M][N] f32
    int M, int N, int K) {
  __shared__ __align__(16) char lds[131072];

  const int t = threadIdx.x;
  const int lane = t & 63;
  const int wv = t >> 6;
  const int wm = wv >> 2;   // 0..1
  const int wn = wv & 3;    // 0..3

  // T1: bijective XCD-aware swizzle (valid since nwg % 8 == 0 is checked)
  const int nwg = gridDim.x;
  const int bid = blockIdx.x;
  const int swz = ((nwg & 7) == 0) ? ((bid & 7) * (nwg >> 3) + (bid >> 3)) : bid;

  const int nbn = N >> 8;
  const int bn = swz % nbn;
  const int bm = swz / nbn;
  const int m0 = bm << 8, n0 = bn << 8;

  // staging: thread t's (row, col) within an 8KB issue (64 rows x 64 cols),
  // carrying the inverse granule swizzle.
  const int rlo = ((t >> 7) << 4) | ((t >> 2) & 15);
  const int gsw = (t & 3) ^ ((t >> 3) & 3);
  const int c0e = (((t >> 6) & 1) << 5) | (gsw << 3);
  const __hip_bfloat16* gA = A + (size_t)(m0 + rlo) * K + c0e;
  const __hip_bfloat16* gB = B + (size_t)(n0 + rlo) * K + c0e;
  const int stBase = wv << 10;  // wave-uniform LDS base; HW adds lane*16

  // ds_read lane bases (swizzled granule)
  const int rho = lane & 15;
  const int gpr = (lane >> 4) ^ ((lane >> 1) & 3);
  const int dsA = (wm << 14) + (rho << 6) + (gpr << 4);
  const int dsB = 32768 + ((wn >> 1) << 14) + ((wn & 1) << 13) + (rho << 6) + (gpr << 4);

#define STAGE(MAT, HALF, G64, KT, BUF)                                                   \
  __builtin_amdgcn_global_load_lds(                                                      \
      (gptr_t)(((MAT) ? gB : gA) + (size_t)((HALF)*128 + (G64)*64) * K + (size_t)(KT)*64), \
      (lptr_t)(lds + (BUF)*LDS_BUF + (MAT)*32768 + (HALF)*16384 + (G64)*8192 + stBase),  \
      16, 0, 0)

#define RD_A(MF, KK, BUF) (*(const bf16x8*)(lds + (BUF)*LDS_BUF + dsA + ((MF)*2 + (KK))*1024))
#define RD_B(NF, KK, BUF) (*(const bf16x8*)(lds + (BUF)*LDS_BUF + dsB + ((NF)*2 + (KK))*1024))
#define BAR() asm volatile("s_barrier" ::: "memory")
#define LOAD_A_PAIR(MF, BUF)                                          \
  a0[0][0] = RD_A(MF, 0, BUF);     a0[0][1] = RD_A(MF, 1, BUF);       \
  a0[1][0] = RD_A((MF)+1, 0, BUF); a0[1][1] = RD_A((MF)+1, 1, BUF)
#define LOAD_B(BUF)                                                   \
  _Pragma("unroll")                                                   \
  for (int nf = 0; nf < 4; nf++) {                                    \
    b0[nf][0] = RD_B(nf, 0, BUF); b0[nf][1] = RD_B(nf, 1, BUF);       \
  }

  f32x4 acc[8][4];
#pragma unroll
  for (int i = 0; i < 8; i++)
#pragma unroll
    for (int j = 0; j < 4; j++) acc[i][j] = (f32x4)(0.0f);

  // ---- prologue: tile 0 fully (8 loads), tile 1 minus A-g0 (6 loads) ----
  STAGE(0, 0, 0, 0, 0); STAGE(0, 0, 1, 0, 0); STAGE(0, 1, 0, 0, 0); STAGE(0, 1, 1, 0, 0);
  STAGE(1, 0, 0, 0, 0); STAGE(1, 0, 1, 0, 0); STAGE(1, 1, 0, 0, 0); STAGE(1, 1, 1, 0, 0);
  STAGE(1, 0, 0, 1, 1); STAGE(1, 0, 1, 1, 1); STAGE(1, 1, 0, 1, 1); STAGE(1, 1, 1, 1, 1);
  STAGE(0, 0, 1, 1, 1); STAGE(0, 1, 1, 1, 1);
  asm volatile("s_waitcnt vmcnt(6)" ::: "memory");
  BAR();

  bf16x8 a0[2][2], b0[4][2];
  // initial frags for phase 0 (tile 0, buf0)
  LOAD_B(0);
  LOAD_A_PAIR(6, 0);

  auto run_iter = [&](int i, auto fullc) {
    constexpr bool FULL = decltype(fullc)::value;
    const int kt1 = 2 * i + 1, kt2 = 2 * i + 2, kt3 = 2 * i + 3;

    // ===== phase 0: tile 2i (buf0), mfrags 6,7 =====
    STAGE(0, 0, 0, kt1, 1); STAGE(0, 1, 0, kt1, 1);
    BAR();
    __builtin_amdgcn_s_setprio(1); mfma16<6>(acc, a0, b0); __builtin_amdgcn_s_setprio(0);
    LOAD_A_PAIR(4, 0);
    BAR();

    // ===== phase 1: mfrags 4,5 =====
    if constexpr (FULL) { STAGE(1, 0, 0, kt2, 0); STAGE(1, 0, 1, kt2, 0); }
    BAR();
    __builtin_amdgcn_s_setprio(1); mfma16<4>(acc, a0, b0); __builtin_amdgcn_s_setprio(0);
    LOAD_A_PAIR(2, 0);
    BAR();

    // ===== phase 2: mfrags 2,3 =====
    if constexpr (FULL) { STAGE(1, 1, 0, kt2, 0); STAGE(1, 1, 1, kt2, 0); }
    BAR();
    __builtin_amdgcn_s_setprio(1); mfma16<2>(acc, a0, b0); __builtin_amdgcn_s_setprio(0);
    LOAD_A_PAIR(0, 0);
    BAR();

    // ===== phase 3: mfrags 0,1; then gated reads of buf1 (tile 2i+1) =====
    if constexpr (FULL) { STAGE(0, 0, 1, kt2, 0); STAGE(0, 1, 1, kt2, 0); }
    BAR();
    __builtin_amdgcn_s_setprio(1); mfma16<0>(acc, a0, b0); __builtin_amdgcn_s_setprio(0);
    if constexpr (FULL) asm volatile("s_waitcnt vmcnt(6)" ::: "memory");
    else                asm volatile("s_waitcnt vmcnt(0)" ::: "memory");
    LOAD_B(1);
    LOAD_A_PAIR(6, 1);
    BAR();

    // ===== phase 4: tile 2i+1 (buf1), mfrags 6,7 =====
    if constexpr (FULL) { STAGE(0, 0, 0, kt2, 0); STAGE(0, 1, 0, kt2, 0); }
    BAR();
    __builtin_amdgcn_s_setprio(1); mfma16<6>(acc, a0, b0); __builtin_amdgcn_s_setprio(0);
    LOAD_A_PAIR(4, 1);
    BAR();

    // ===== phase 5: mfrags 4,5 =====
    if constexpr (FULL) { STAGE(1, 0, 0, kt3, 1); STAGE(1, 0, 1, kt3, 1); }
    BAR();
    __builtin_amdgcn_s_setprio(1); mfma16<4>(acc, a0, b0); __builtin_amdgcn_s_setprio(0);
    LOAD_A_PAIR(2, 1);
    BAR();

    // ===== phase 6: mfrags 2,3 =====
    if constexpr (FULL) { STAGE(1, 1, 0, kt3, 1); STAGE(1, 1, 1, kt3, 1); }
    BAR();
    __builtin_amdgcn_s_setprio(1); mfma16<2>(acc, a0, b0); __builtin_amdgcn_s_setprio(0);
    LOAD_A_PAIR(0, 1);
    BAR();

    // ===== phase 7: mfrags 0,1; then gated reads of buf0 (tile 2i+2) =====
    if constexpr (FULL) { STAGE(0, 0, 1, kt3, 1); STAGE(0, 1, 1, kt3, 1); }
    BAR();
    __builtin_amdgcn_s_setprio(1); mfma16<0>(acc, a0, b0); __builtin_amdgcn_s_setprio(0);
    if constexpr (FULL) {
      asm volatile("s_waitcnt vmcnt(6)" ::: "memory");
      LOAD_B(0);
      LOAD_A_PAIR(6, 0);
    }
    BAR();
  };

  const int half_nt = K >> 7;
  for (int i = 0; i < half_nt - 1; ++i) run_iter(i, BoolC<true>{});
  run_iter(half_nt - 1, BoolC<false>{});

  // ---- epilogue: C/D layout col=lane&15, row=(lane>>4)*4+j ----
  const int cc = lane & 15;
  const int cr4 = (lane >> 4) << 2;
#pragma unroll
  for (int nf = 0; nf < 4; nf++) {
    const int col = n0 + wn * 64 + nf * 16 + cc;
    const float s = scale[col];
#pragma unroll
    for (int mf = 0; mf < 8; mf++) {
      const int row = m0 + wm * 128 + mf * 16 + cr4;
#pragma unroll
      for (int j = 0; j < 4; j++)
        C[(size_t)(row + j) * N + col] = acc[mf][nf][j] * s;
    }
  }
#undef STAGE
#undef RD_A
#undef RD_B
#undef BAR
#undef LOAD_A_PAIR
#undef LOAD_B
}

// ---- fallback: f32 tiled GEMM (odd shapes / tiny ws) ----
__global__ __launch_bounds__(256) void fallback_gemm_kernel(
    const float* __restrict__ x, const float* __restrict__ w,
    const float* __restrict__ scale, float* __restrict__ out,
    int M, int N, int K) {
  __shared__ float xs[16][17];
  __shared__ float ws_[16][17];
  int nb = N / 16;
  int bx = blockIdx.x % nb;
  int by = blockIdx.x / nb;
  int tx = threadIdx.x % 16;
  int ty = threadIdx.x / 16;
  float acc = 0.f;
  for (int k0 = 0; k0 < K; k0 += 16) {
    xs[ty][tx] = x[(size_t)(by * 16 + ty) * K + k0 + tx];
    float wv = w[(size_t)(bx * 16 + ty) * K + k0 + tx];
    ws_[ty][tx] = (float)((wv > 0.f) - (wv < 0.f));
    __syncthreads();
#pragma unroll
    for (int kk = 0; kk < 16; kk++) acc += xs[ty][kk] * ws_[tx][kk];
    __syncthreads();
  }
  int row = by * 16 + ty, col = bx * 16 + tx;
  out[(size_t)row * N + col] = acc * scale[col];
}

extern "C" void kernel_launch(void* const* d_in, const int* in_sizes, int n_in,
                              void* d_out, int out_size, void* d_ws, size_t ws_size,
                              hipStream_t stream) {
  const float* x = (const float*)d_in[0];
  const float* w = (const float*)d_in[1];
  const float* scale = (const float*)d_in[2];
  float* out = (float*)d_out;

  const int N = in_sizes[2];
  const int K = in_sizes[1] / N;
  const int M = in_sizes[0] / K;

  const size_t xb_bytes = (size_t)M * K * 2;
  const size_t wb_bytes = (size_t)N * K * 2;
  const bool shapes_ok = (M % 256 == 0) && (N % 256 == 0) && (K % 128 == 0);

  if (shapes_ok && ws_size >= xb_bytes + wb_bytes) {
    __hip_bfloat16* xb = (__hip_bfloat16*)d_ws;
    __hip_bfloat16* wb = (__hip_bfloat16*)((char*)d_ws + xb_bytes);

    cvt_x_kernel<<<2048, 256, 0, stream>>>((const float4*)x, (ushort4*)xb, M * (K / 4));
    binarize_w_kernel<<<2048, 256, 0, stream>>>((const float4*)w, (ushort4*)wb, N * (K / 4));

    int grid = (M / 256) * (N / 256);
    gemm256_kernel<<<grid, 512, 0, stream>>>(xb, wb, scale, out, M, N, K);
  } else {
    int grid = (M / 16) * (N / 16);
    fallback_gemm_kernel<<<grid, 256, 0, stream>>>(x, w, scale, out, M, N, K);
  }
}